// Round 8
// baseline (282.747 us; speedup 1.0000x reference)
//
#include <hip/hip_runtime.h>
#include <stdint.h>
#include <stddef.h>

#define NN 50000
#define NP 50048            // padded rows (782 * 64) so MFMA A-frag OOB reads stay in-buffer
#define NE 800000
#define NG 128

#define NBKT 256            // dst buckets
#define NPB 196             // nodes per bucket (196*256 = 50176 >= NN)
#define BCAP 4096           // bucket capacity (mean ~3125 + 17 sigma)
#define TILE_E 3072         // edges per partition workgroup
#define PARTB 261           // ceil(NE / TILE_E)
#define CVTB 4688           // ceil(NN*96/4 / 256)
#define AGB 3125            // agg blocks per chunk (3125 * 16 nodes = 50000)
#define TFB 782             // transform blocks (NP/64)

typedef __attribute__((ext_vector_type(8))) short bf16x8;
typedef __attribute__((ext_vector_type(4))) float f32x4;
typedef __attribute__((ext_vector_type(4))) unsigned int u32x4;
typedef unsigned short ushort_t;
typedef unsigned int uint_t;

// float -> bf16 (RNE) and bf16x2 unpack helpers
static __device__ inline ushort_t f2b(float f) {
    union { float f; uint_t u; } v; v.f = f;
    uint_t r = v.u + 0x7FFFu + ((v.u >> 16) & 1u);
    return (ushort_t)(r >> 16);
}
static __device__ inline float blo(uint_t u) {
    union { uint_t u; float f; } v; v.u = u << 16; return v.f;
}
static __device__ inline float bhi(uint_t u) {
    union { uint_t u; float f; } v; v.u = u & 0xFFFF0000u; return v.f;
}

// ---------------- K1: partition (blocks 0..PARTB-1) + cvt (rest) ----------------
// partition first so csr_build's dependency completes ASAP.
__launch_bounds__(256) static __global__
void cvt_part_kernel(const float* __restrict__ x, ushort_t* __restrict__ xb,
                     const int* __restrict__ src, const int* __restrict__ dst,
                     int* __restrict__ bucket_cnt, uint_t* __restrict__ part) {
    __shared__ int hist[NBKT];
    int tid = threadIdx.x;
    if (blockIdx.x < PARTB) {
        // two-pass partition: no per-thread arrays -> no scratch spill (R7)
        hist[tid] = 0;
        __syncthreads();
        int base = blockIdx.x * TILE_E;
        int end = min(base + TILE_E, NE);
        for (int i = base + tid; i < end; i += 256)
            atomicAdd(&hist[dst[i] / NPB], 1);
        __syncthreads();
        int r = atomicAdd(&bucket_cnt[tid], hist[tid]);   // reserve
        __syncthreads();
        hist[tid] = r;                                    // reuse as cursor
        __syncthreads();
        for (int i = base + tid; i < end; i += 256) {
            int s = src[i], d = dst[i];
            int b = d / NPB;
            int dl = d - b * NPB;
            int p = atomicAdd(&hist[b], 1);
            part[b * BCAP + p] = ((uint_t)dl << 16) | (uint_t)s;
        }
    } else {
        int gid = (blockIdx.x - PARTB) * 256 + tid;
        int i = gid * 4;
        if (i + 3 < NN * 96) {
            float4 v = *(const float4*)(x + i);
            ushort_t o0 = f2b(v.x), o1 = f2b(v.y), o2 = f2b(v.z), o3 = f2b(v.w);
            uint_t lo = (uint_t)o0 | ((uint_t)o1 << 16);
            uint_t hi = (uint_t)o2 | ((uint_t)o3 << 16);
            *(uint2*)(xb + i) = make_uint2(lo, hi);
        }
    }
}

// ---------------- csr_build body (per-bucket CSR + deg + offs) ----------------
static __device__ void csr_build_body(int b, char* smem, const uint_t* __restrict__ part,
                                      const int* __restrict__ bucket_cnt, int* __restrict__ deg,
                                      int* __restrict__ offs, int* __restrict__ csr) {
    uint_t* stage = (uint_t*)smem;                       // 16384 B
    ushort_t* cstage = (ushort_t*)(smem + 16384);        // 8192 B
    int* cnt_s = (int*)(smem + 24576);                   // 1024 B
    int* scan_l = (int*)(smem + 25600);                  // 1024 B
    int* cur_l = (int*)(smem + 26624);                   // 1024 B
    int tid = threadIdx.x;
    int bc = bucket_cnt[tid];
    cnt_s[tid] = bc;
    scan_l[tid] = bc;
    __syncthreads();
    for (int off = 1; off < NBKT; off <<= 1) {
        int t = (tid >= off) ? scan_l[tid - off] : 0;
        __syncthreads();
        scan_l[tid] += t;
        __syncthreads();
    }
    int base = scan_l[b] - cnt_s[b];
    int n = cnt_s[b];
    __syncthreads();
    cnt_s[tid] = 0;                           // reuse as deg_l
    __syncthreads();
    for (int i = tid; i < n; i += 256) {
        uint_t e = part[(size_t)b * BCAP + i];
        stage[i] = e;
        atomicAdd(&cnt_s[e >> 16], 1);
    }
    __syncthreads();
    int v = cnt_s[tid];
    scan_l[tid] = v;
    __syncthreads();
    for (int off = 1; off < NBKT; off <<= 1) {
        int t = (tid >= off) ? scan_l[tid - off] : 0;
        __syncthreads();
        scan_l[tid] += t;
        __syncthreads();
    }
    int ex = scan_l[tid] - v;
    scan_l[tid] = ex;
    cur_l[tid] = 0;
    __syncthreads();
    int g = b * NPB + tid;
    if (tid < NPB && g < NN) { deg[g] = v; offs[g] = base + ex; }
    for (int i = tid; i < n; i += 256) {
        uint_t e = stage[i];
        int dl = e >> 16;
        int p = atomicAdd(&cur_l[dl], 1);
        cstage[scan_l[dl] + p] = (ushort_t)(e & 0xFFFFu);
    }
    __syncthreads();
    for (int i = tid; i < n; i += 256) csr[base + i] = (int)cstage[i];
}

// ---------------- MFMA transform body (R4 design, chunk-major outputs) ----------------
// Outputs chunk-major: tlc[(c*NN + node)*32 + f], c = o>>5, f = o&31 (3.2 MB
// per chunk -> agg gather set is L2-sized).
template <int DOUT, int NT>   // OT = 2*DOUT = NT*16, DIN = 96
static __device__ void transform_body(int bid, char* smem,
                                      const ushort_t* __restrict__ hb, const float* __restrict__ Wl,
                                      const float* __restrict__ bias, const float* __restrict__ Wr,
                                      ushort_t* __restrict__ tlc, ushort_t* __restrict__ trc) {
    constexpr int DIN = 96;
    short* w_s = (short*)smem;                // NT*3*64*8 shorts (<= 36864 B)
    int tid = threadIdx.x;
    for (int idx = tid; idx < NT * 3 * 64; idx += 256) {
        int ci = idx >> 6, ln = idx & 63;
        int t = ci / 3, s = ci - 3 * t;
        int o = t * 16 + (ln & 15);
        int c0 = s * 32 + (ln >> 4) * 8;
        const float* wrow = (o < DOUT) ? (Wl + (size_t)o * DIN)
                                       : (Wr + (size_t)(o - DOUT) * DIN);
        float4 v0 = *(const float4*)(wrow + c0);
        float4 v1 = *(const float4*)(wrow + c0 + 4);
        bf16x8 pk;
        pk[0] = (short)f2b(v0.x); pk[1] = (short)f2b(v0.y);
        pk[2] = (short)f2b(v0.z); pk[3] = (short)f2b(v0.w);
        pk[4] = (short)f2b(v1.x); pk[5] = (short)f2b(v1.y);
        pk[6] = (short)f2b(v1.z); pk[7] = (short)f2b(v1.w);
        *(bf16x8*)&w_s[idx * 8] = pk;
    }
    int lane = tid & 63;
    int m0 = bid * 64 + (tid >> 6) * 16;
    int row = m0 + (lane & 15);
    const bf16x8* arow = (const bf16x8*)(hb + (size_t)row * DIN) + (lane >> 4);
    bf16x8 a0 = arow[0];
    bf16x8 a1 = arow[4];
    bf16x8 a2 = arow[8];
    __syncthreads();
    const bf16x8* wp = (const bf16x8*)w_s + lane;
    f32x4 acc[NT];
#pragma unroll
    for (int t = 0; t < NT; t++) {
        acc[t] = (f32x4){0.f, 0.f, 0.f, 0.f};
        acc[t] = __builtin_amdgcn_mfma_f32_16x16x32_bf16(a0, wp[(t * 3 + 0) * 64], acc[t], 0, 0, 0);
        acc[t] = __builtin_amdgcn_mfma_f32_16x16x32_bf16(a1, wp[(t * 3 + 1) * 64], acc[t], 0, 0, 0);
        acc[t] = __builtin_amdgcn_mfma_f32_16x16x32_bf16(a2, wp[(t * 3 + 2) * 64], acc[t], 0, 0, 0);
    }
    int quad = lane >> 4, col = lane & 15;
#pragma unroll
    for (int t = 0; t < NT; t++) {
        int o = t * 16 + col;
        bool is_r = (o >= DOUT);
        float bv = is_r ? bias[o - DOUT] : 0.f;
        ushort_t* outp = is_r ? trc : tlc;
        int oo = is_r ? (o - DOUT) : o;
        int cch = oo >> 5, f = oo & 31;
        ushort_t* ob = outp + ((size_t)cch * NN) * 32 + f;
#pragma unroll
        for (int r = 0; r < 4; r++) {
            int node = m0 + quad * 4 + r;
            if (node < NN) ob[(size_t)node * 32] = f2b(acc[t][r] + bv);
        }
    }
}

// ---------------- K2: csr_build (blocks 0..255) + transform layer0 (rest) ----------------
__launch_bounds__(256) static __global__
void csr_tf0_kernel(const uint_t* __restrict__ part, const int* __restrict__ bucket_cnt,
                    int* __restrict__ deg, int* __restrict__ offs, int* __restrict__ csr,
                    const ushort_t* __restrict__ xb, const float* __restrict__ Wl0,
                    const float* __restrict__ b0, const float* __restrict__ Wr0,
                    ushort_t* __restrict__ tlc, ushort_t* __restrict__ trc) {
    __shared__ __align__(16) char smem[36864];
    if (blockIdx.x < NBKT)
        csr_build_body(blockIdx.x, smem, part, bucket_cnt, deg, offs, csr);
    else
        transform_body<96, 12>(blockIdx.x - NBKT, smem, xb, Wl0, b0, Wr0, tlc, trc);
}

// standalone transform (layers 1,2)
template <int DOUT, int NT>
__launch_bounds__(256, 4) static __global__
void transform_kernel(const ushort_t* __restrict__ hb, const float* __restrict__ Wl,
                      const float* __restrict__ bias, const float* __restrict__ Wr,
                      ushort_t* __restrict__ tlc, ushort_t* __restrict__ trc) {
    __shared__ __align__(16) char smem[NT * 3 * 64 * 8 * 2];
    transform_body<DOUT, NT>(blockIdx.x, smem, hb, Wl, bias, Wr, tlc, trc);
}

// ---------------- chunked aggregation ----------------
// One 32-feature chunk per grid segment (chunk = blockIdx.x / AGB): gather set
// = 3.2 MB, L2-sized. tr reads and out writes are NONTEMPORAL so these streams
// don't evict the gather set (R7 post-mortem: streams thrash the chunk).
// 16 lanes/node = 4 neighbor-groups x 4 feature-lanes; one dwordx4 per lane
// covers the 64B row among 4 lanes; shfl_xor(4,8) cross-group reduce.
template <int D, bool RELU, bool OUT_BF16>
__launch_bounds__(256) static __global__
void agg3_kernel(const ushort_t* __restrict__ tlc, const ushort_t* __restrict__ trc,
                 const int* __restrict__ offs, const int* __restrict__ deg,
                 const int* __restrict__ csr, void* __restrict__ outv) {
    int bx = blockIdx.x;
    int c = bx / AGB;
    int b = bx - c * AGB;
    int tid = threadIdx.x;
    int node = b * 16 + (tid >> 4);
    int lane = tid & 15;
    int ng = lane >> 2, fl = lane & 3;
    const uint_t* tl = (const uint_t*)tlc + (size_t)c * NN * 16;
    int off = offs[node], dg = deg[node];
    float acc[8];
#pragma unroll
    for (int q = 0; q < 8; q++) acc[q] = 0.f;
    int k = 0;
    for (; k + 8 <= dg; k += 8) {
        int s0 = csr[off + k + ng];
        int s1 = csr[off + k + 4 + ng];
        uint4 a0 = *(const uint4*)(tl + (size_t)s0 * 16 + 4 * fl);
        uint4 a1 = *(const uint4*)(tl + (size_t)s1 * 16 + 4 * fl);
        acc[0] += blo(a0.x) + blo(a1.x); acc[1] += bhi(a0.x) + bhi(a1.x);
        acc[2] += blo(a0.y) + blo(a1.y); acc[3] += bhi(a0.y) + bhi(a1.y);
        acc[4] += blo(a0.z) + blo(a1.z); acc[5] += bhi(a0.z) + bhi(a1.z);
        acc[6] += blo(a0.w) + blo(a1.w); acc[7] += bhi(a0.w) + bhi(a1.w);
    }
    if (k + 4 <= dg) {
        int s0 = csr[off + k + ng];
        uint4 a0 = *(const uint4*)(tl + (size_t)s0 * 16 + 4 * fl);
        acc[0] += blo(a0.x); acc[1] += bhi(a0.x);
        acc[2] += blo(a0.y); acc[3] += bhi(a0.y);
        acc[4] += blo(a0.z); acc[5] += bhi(a0.z);
        acc[6] += blo(a0.w); acc[7] += bhi(a0.w);
        k += 4;
    }
    if (ng < dg - k) {
        int s0 = csr[off + k + ng];
        uint4 a0 = *(const uint4*)(tl + (size_t)s0 * 16 + 4 * fl);
        acc[0] += blo(a0.x); acc[1] += bhi(a0.x);
        acc[2] += blo(a0.y); acc[3] += bhi(a0.y);
        acc[4] += blo(a0.z); acc[5] += bhi(a0.z);
        acc[6] += blo(a0.w); acc[7] += bhi(a0.w);
    }
#pragma unroll
    for (int q = 0; q < 8; q++) {
        acc[q] += __shfl_xor(acc[q], 4, 64);
        acc[q] += __shfl_xor(acc[q], 8, 64);
    }
    float s = 1.f / (float)max(dg, 1);
    u32x4 t = __builtin_nontemporal_load(
        (const u32x4*)((const uint_t*)trc + (size_t)c * NN * 16 + (size_t)node * 16 + 4 * fl));
    float v0 = fmaf(acc[0], s, blo(t.x));
    float v1 = fmaf(acc[1], s, bhi(t.x));
    float v2 = fmaf(acc[2], s, blo(t.y));
    float v3 = fmaf(acc[3], s, bhi(t.y));
    float v4 = fmaf(acc[4], s, blo(t.z));
    float v5 = fmaf(acc[5], s, bhi(t.z));
    float v6 = fmaf(acc[6], s, blo(t.w));
    float v7 = fmaf(acc[7], s, bhi(t.w));
    if (RELU) {
        v0 = fmaxf(v0, 0.f); v1 = fmaxf(v1, 0.f); v2 = fmaxf(v2, 0.f); v3 = fmaxf(v3, 0.f);
        v4 = fmaxf(v4, 0.f); v5 = fmaxf(v5, 0.f); v6 = fmaxf(v6, 0.f); v7 = fmaxf(v7, 0.f);
    }
    if (ng == 0) {
        if (OUT_BF16) {
            // next-layer input layout: [node][96] bf16
            u32x4 o;
            o.x = (uint_t)f2b(v0) | ((uint_t)f2b(v1) << 16);
            o.y = (uint_t)f2b(v2) | ((uint_t)f2b(v3) << 16);
            o.z = (uint_t)f2b(v4) | ((uint_t)f2b(v5) << 16);
            o.w = (uint_t)f2b(v6) | ((uint_t)f2b(v7) << 16);
            __builtin_nontemporal_store(
                o, (u32x4*)((uint_t*)outv + (size_t)node * (D / 2) + c * 16 + 4 * fl));
        } else {
            float* op = (float*)outv + (size_t)node * D + c * 32 + 8 * fl;
            __builtin_nontemporal_store((f32x4){v0, v1, v2, v3}, (f32x4*)op);
            __builtin_nontemporal_store((f32x4){v4, v5, v6, v7}, (f32x4*)(op + 4));
        }
    }
}

// ---------------- pool: one block per graph, binary-searched node range ----------------
// batch is sorted; no atomics, no accum/finalize pass.
__launch_bounds__(256) static __global__
void pool_kernel(const float* __restrict__ h, const int* __restrict__ batch,
                 float* __restrict__ out) {
    __shared__ float red[256];
    int g = blockIdx.x, tid = threadIdx.x;
    int lo = 0, hi = NN;
    while (lo < hi) { int mid = (lo + hi) >> 1; if (batch[mid] < g) lo = mid + 1; else hi = mid; }
    int start = lo;
    hi = NN;
    while (lo < hi) { int mid = (lo + hi) >> 1; if (batch[mid] < g + 1) lo = mid + 1; else hi = mid; }
    int end = lo;
    int c = tid & 63, j = tid >> 6;
    float acc = 0.f;
    for (int i = start + j; i < end; i += 4) acc += h[(size_t)i * 64 + c];
    red[tid] = acc;
    __syncthreads();
    if (tid < 64) {
        float v = red[tid] + red[tid + 64] + red[tid + 128] + red[tid + 192];
        out[g * 64 + tid] = v / (float)max(end - start, 1);
    }
}

// ---------------- launch ----------------
extern "C" void kernel_launch(void* const* d_in, const int* in_sizes, int n_in,
                              void* d_out, int out_size, void* d_ws, size_t ws_size,
                              hipStream_t stream) {
    (void)in_sizes; (void)n_in; (void)out_size; (void)ws_size;
    const float* x   = (const float*)d_in[0];
    const int*   ei  = (const int*)d_in[1];
    const int*   bat = (const int*)d_in[2];
    const float* Wl0 = (const float*)d_in[3];
    const float* b0  = (const float*)d_in[4];
    const float* Wr0 = (const float*)d_in[5];
    const float* Wl1 = (const float*)d_in[6];
    const float* b1  = (const float*)d_in[7];
    const float* Wr1 = (const float*)d_in[8];
    const float* Wl2 = (const float*)d_in[9];
    const float* b2  = (const float*)d_in[10];
    const float* Wr2 = (const float*)d_in[11];
    float* out = (float*)d_out;
    const int* src = ei;
    const int* dst = ei + NE;

    char* p = (char*)d_ws;
    auto carve = [&](size_t bytes) -> char* {
        char* r = p;
        p += (bytes + 255) & ~(size_t)255;
        return r;
    };
    int*      deg    = (int*)carve((size_t)NN * 4);
    int*      offs   = (int*)carve((size_t)NN * 4);
    int*      bucket_cnt = (int*)carve(NBKT * 4);
    uint_t*   part   = (uint_t*)carve((size_t)NBKT * BCAP * 4);
    int*      csr    = (int*)carve((size_t)NE * 4);
    ushort_t* xb     = (ushort_t*)carve((size_t)NP * 96 * 2);   // layer-0 input; reused as h2b
    ushort_t* h1b    = (ushort_t*)carve((size_t)NP * 96 * 2);
    ushort_t* tlc    = (ushort_t*)carve((size_t)3 * NN * 32 * 2);  // chunk-major
    ushort_t* trc    = (ushort_t*)carve((size_t)3 * NN * 32 * 2);  // chunk-major
    float*    Hf     = (float*)carve((size_t)NN * 64 * 4);

    dim3 b256(256);
    hipMemsetAsync(bucket_cnt, 0, NBKT * 4, stream);

    cvt_part_kernel<<<dim3(PARTB + CVTB), b256, 0, stream>>>(x, xb, src, dst, bucket_cnt, part);
    csr_tf0_kernel<<<dim3(NBKT + TFB), b256, 0, stream>>>(part, bucket_cnt, deg, offs, csr,
                                                          xb, Wl0, b0, Wr0, tlc, trc);
    agg3_kernel<96, true, true><<<dim3(3 * AGB), b256, 0, stream>>>(tlc, trc, offs, deg, csr, h1b);
    transform_kernel<96, 12><<<dim3(TFB), b256, 0, stream>>>(h1b, Wl1, b1, Wr1, tlc, trc);
    agg3_kernel<96, true, true><<<dim3(3 * AGB), b256, 0, stream>>>(tlc, trc, offs, deg, csr, xb);
    transform_kernel<64, 8><<<dim3(TFB), b256, 0, stream>>>(xb, Wl2, b2, Wr2, tlc, trc);
    agg3_kernel<64, false, false><<<dim3(2 * AGB), b256, 0, stream>>>(tlc, trc, offs, deg, csr, Hf);
    pool_kernel<<<dim3(NG), b256, 0, stream>>>(Hf, bat, out);
}

// Round 10
// 249.630 us; speedup vs baseline: 1.1327x; 1.1327x over previous
//
#include <hip/hip_runtime.h>
#include <stdint.h>
#include <stddef.h>

#define NN 50000
#define NP 50048            // padded rows (782 * 64) so MFMA A-frag OOB reads stay in-buffer
#define NE 800000
#define NG 128

#define NBKT 256            // dst buckets
#define NPB 196             // nodes per bucket (196*256 = 50176 >= NN)
#define BCAP 4096           // bucket capacity (mean ~3125 + 17 sigma)
#define TILE_E 3072         // edges per partition workgroup
#define PARTB 261           // ceil(NE / TILE_E)
#define CVTB 4688           // ceil(NN*96/4 / 256)
#define AGB 3125            // agg blocks per chunk (3125 * 16 nodes = 50000)
#define TFB 782             // transform blocks (NP/64)
#define POOLB 1024          // pool blocks (49 nodes each)

typedef __attribute__((ext_vector_type(8))) short bf16x8;
typedef __attribute__((ext_vector_type(4))) float f32x4;
typedef __attribute__((ext_vector_type(4))) unsigned int u32x4;
typedef unsigned short ushort_t;
typedef unsigned int uint_t;

// float -> bf16 (RNE) and bf16x2 unpack helpers
static __device__ inline ushort_t f2b(float f) {
    union { float f; uint_t u; } v; v.f = f;
    uint_t r = v.u + 0x7FFFu + ((v.u >> 16) & 1u);
    return (ushort_t)(r >> 16);
}
static __device__ inline float blo(uint_t u) {
    union { uint_t u; float f; } v; v.u = u << 16; return v.f;
}
static __device__ inline float bhi(uint_t u) {
    union { uint_t u; float f; } v; v.u = u & 0xFFFF0000u; return v.f;
}

// ---------------- K1: partition (blocks 0..PARTB-1) + cvt + zero accum (rest) --------
__launch_bounds__(256) static __global__
void cvt_part_kernel(const float* __restrict__ x, ushort_t* __restrict__ xb,
                     const int* __restrict__ src, const int* __restrict__ dst,
                     int* __restrict__ bucket_cnt, uint_t* __restrict__ part,
                     float* __restrict__ accum) {
    __shared__ int hist[NBKT];
    int tid = threadIdx.x;
    if (blockIdx.x < PARTB) {
        // two-pass partition: no per-thread arrays -> no scratch spill (R7)
        hist[tid] = 0;
        __syncthreads();
        int base = blockIdx.x * TILE_E;
        int end = min(base + TILE_E, NE);
        for (int i = base + tid; i < end; i += 256)
            atomicAdd(&hist[dst[i] / NPB], 1);
        __syncthreads();
        int r = atomicAdd(&bucket_cnt[tid], hist[tid]);   // reserve
        __syncthreads();
        hist[tid] = r;                                    // reuse as cursor
        __syncthreads();
        for (int i = base + tid; i < end; i += 256) {
            int s = src[i], d = dst[i];
            int b = d / NPB;
            int dl = d - b * NPB;
            int p = atomicAdd(&hist[b], 1);
            part[b * BCAP + p] = ((uint_t)dl << 16) | (uint_t)s;
        }
    } else {
        int gid = (blockIdx.x - PARTB) * 256 + tid;
        if (gid < NG * 64) accum[gid] = 0.f;
        int i = gid * 4;
        if (i + 3 < NN * 96) {
            float4 v = *(const float4*)(x + i);
            ushort_t o0 = f2b(v.x), o1 = f2b(v.y), o2 = f2b(v.z), o3 = f2b(v.w);
            uint_t lo = (uint_t)o0 | ((uint_t)o1 << 16);
            uint_t hi = (uint_t)o2 | ((uint_t)o3 << 16);
            *(uint2*)(xb + i) = make_uint2(lo, hi);
        }
    }
}

// ---------------- csr_build body (per-bucket CSR + deg + offs) ----------------
static __device__ void csr_build_body(int b, char* smem, const uint_t* __restrict__ part,
                                      const int* __restrict__ bucket_cnt, int* __restrict__ deg,
                                      int* __restrict__ offs, int* __restrict__ csr) {
    uint_t* stage = (uint_t*)smem;                       // 16384 B
    ushort_t* cstage = (ushort_t*)(smem + 16384);        // 8192 B
    int* cnt_s = (int*)(smem + 24576);                   // 1024 B
    int* scan_l = (int*)(smem + 25600);                  // 1024 B
    int* cur_l = (int*)(smem + 26624);                   // 1024 B
    int tid = threadIdx.x;
    int bc = bucket_cnt[tid];
    cnt_s[tid] = bc;
    scan_l[tid] = bc;
    __syncthreads();
    for (int off = 1; off < NBKT; off <<= 1) {
        int t = (tid >= off) ? scan_l[tid - off] : 0;
        __syncthreads();
        scan_l[tid] += t;
        __syncthreads();
    }
    int base = scan_l[b] - cnt_s[b];
    int n = cnt_s[b];
    __syncthreads();
    cnt_s[tid] = 0;                           // reuse as deg_l
    __syncthreads();
    for (int i = tid; i < n; i += 256) {
        uint_t e = part[(size_t)b * BCAP + i];
        stage[i] = e;
        atomicAdd(&cnt_s[e >> 16], 1);
    }
    __syncthreads();
    int v = cnt_s[tid];
    scan_l[tid] = v;
    __syncthreads();
    for (int off = 1; off < NBKT; off <<= 1) {
        int t = (tid >= off) ? scan_l[tid - off] : 0;
        __syncthreads();
        scan_l[tid] += t;
        __syncthreads();
    }
    int ex = scan_l[tid] - v;
    scan_l[tid] = ex;
    cur_l[tid] = 0;
    __syncthreads();
    int g = b * NPB + tid;
    if (tid < NPB && g < NN) { deg[g] = v; offs[g] = base + ex; }
    for (int i = tid; i < n; i += 256) {
        uint_t e = stage[i];
        int dl = e >> 16;
        int p = atomicAdd(&cur_l[dl], 1);
        cstage[scan_l[dl] + p] = (ushort_t)(e & 0xFFFFu);
    }
    __syncthreads();
    for (int i = tid; i < n; i += 256) csr[base + i] = (int)cstage[i];
}

// ---------------- MFMA transform body (R4 design, chunk-major outputs) ----------------
// Outputs chunk-major: tlc[(c*NN + node)*32 + f], c = o>>5, f = o&31 (3.2 MB
// per chunk -> agg gather set is L2-sized).
template <int DOUT, int NT>   // OT = 2*DOUT = NT*16, DIN = 96
static __device__ void transform_body(int bid, char* smem,
                                      const ushort_t* __restrict__ hb, const float* __restrict__ Wl,
                                      const float* __restrict__ bias, const float* __restrict__ Wr,
                                      ushort_t* __restrict__ tlc, ushort_t* __restrict__ trc) {
    constexpr int DIN = 96;
    short* w_s = (short*)smem;                // NT*3*64*8 shorts (<= 36864 B)
    int tid = threadIdx.x;
    for (int idx = tid; idx < NT * 3 * 64; idx += 256) {
        int ci = idx >> 6, ln = idx & 63;
        int t = ci / 3, s = ci - 3 * t;
        int o = t * 16 + (ln & 15);
        int c0 = s * 32 + (ln >> 4) * 8;
        const float* wrow = (o < DOUT) ? (Wl + (size_t)o * DIN)
                                       : (Wr + (size_t)(o - DOUT) * DIN);
        float4 v0 = *(const float4*)(wrow + c0);
        float4 v1 = *(const float4*)(wrow + c0 + 4);
        bf16x8 pk;
        pk[0] = (short)f2b(v0.x); pk[1] = (short)f2b(v0.y);
        pk[2] = (short)f2b(v0.z); pk[3] = (short)f2b(v0.w);
        pk[4] = (short)f2b(v1.x); pk[5] = (short)f2b(v1.y);
        pk[6] = (short)f2b(v1.z); pk[7] = (short)f2b(v1.w);
        *(bf16x8*)&w_s[idx * 8] = pk;
    }
    int lane = tid & 63;
    int m0 = bid * 64 + (tid >> 6) * 16;
    int row = m0 + (lane & 15);
    const bf16x8* arow = (const bf16x8*)(hb + (size_t)row * DIN) + (lane >> 4);
    bf16x8 a0 = arow[0];
    bf16x8 a1 = arow[4];
    bf16x8 a2 = arow[8];
    __syncthreads();
    const bf16x8* wp = (const bf16x8*)w_s + lane;
    f32x4 acc[NT];
#pragma unroll
    for (int t = 0; t < NT; t++) {
        acc[t] = (f32x4){0.f, 0.f, 0.f, 0.f};
        acc[t] = __builtin_amdgcn_mfma_f32_16x16x32_bf16(a0, wp[(t * 3 + 0) * 64], acc[t], 0, 0, 0);
        acc[t] = __builtin_amdgcn_mfma_f32_16x16x32_bf16(a1, wp[(t * 3 + 1) * 64], acc[t], 0, 0, 0);
        acc[t] = __builtin_amdgcn_mfma_f32_16x16x32_bf16(a2, wp[(t * 3 + 2) * 64], acc[t], 0, 0, 0);
    }
    int quad = lane >> 4, col = lane & 15;
#pragma unroll
    for (int t = 0; t < NT; t++) {
        int o = t * 16 + col;
        bool is_r = (o >= DOUT);
        float bv = is_r ? bias[o - DOUT] : 0.f;
        ushort_t* outp = is_r ? trc : tlc;
        int oo = is_r ? (o - DOUT) : o;
        int cch = oo >> 5, f = oo & 31;
        ushort_t* ob = outp + ((size_t)cch * NN) * 32 + f;
#pragma unroll
        for (int r = 0; r < 4; r++) {
            int node = m0 + quad * 4 + r;
            if (node < NN) ob[(size_t)node * 32] = f2b(acc[t][r] + bv);
        }
    }
}

// ---------------- K2: csr_build (blocks 0..255) + transform layer0 (rest) ----------------
__launch_bounds__(256) static __global__
void csr_tf0_kernel(const uint_t* __restrict__ part, const int* __restrict__ bucket_cnt,
                    int* __restrict__ deg, int* __restrict__ offs, int* __restrict__ csr,
                    const ushort_t* __restrict__ xb, const float* __restrict__ Wl0,
                    const float* __restrict__ b0, const float* __restrict__ Wr0,
                    ushort_t* __restrict__ tlc, ushort_t* __restrict__ trc) {
    __shared__ __align__(16) char smem[36864];
    if (blockIdx.x < NBKT)
        csr_build_body(blockIdx.x, smem, part, bucket_cnt, deg, offs, csr);
    else
        transform_body<96, 12>(blockIdx.x - NBKT, smem, xb, Wl0, b0, Wr0, tlc, trc);
}

// standalone transform (layers 1,2)
template <int DOUT, int NT>
__launch_bounds__(256, 4) static __global__
void transform_kernel(const ushort_t* __restrict__ hb, const float* __restrict__ Wl,
                      const float* __restrict__ bias, const float* __restrict__ Wr,
                      ushort_t* __restrict__ tlc, ushort_t* __restrict__ trc) {
    __shared__ __align__(16) char smem[NT * 3 * 64 * 8 * 2];
    transform_body<DOUT, NT>(blockIdx.x, smem, hb, Wl, bias, Wr, tlc, trc);
}

// ---------------- chunked aggregation ----------------
// One 32-feature chunk per grid segment (chunk = blockIdx.x / AGB): gather set
// = 3.2 MB, L2-sized. tr reads and out writes are NONTEMPORAL so these streams
// don't evict the gather set. 16 lanes/node = 4 neighbor-groups x 4
// feature-lanes; one dwordx4 per lane; shfl_xor(4,8) cross-group reduce.
template <int D, bool RELU, bool OUT_BF16>
__launch_bounds__(256) static __global__
void agg3_kernel(const ushort_t* __restrict__ tlc, const ushort_t* __restrict__ trc,
                 const int* __restrict__ offs, const int* __restrict__ deg,
                 const int* __restrict__ csr, void* __restrict__ outv) {
    int bx = blockIdx.x;
    int c = bx / AGB;
    int b = bx - c * AGB;
    int tid = threadIdx.x;
    int node = b * 16 + (tid >> 4);
    int lane = tid & 15;
    int ng = lane >> 2, fl = lane & 3;
    const uint_t* tl = (const uint_t*)tlc + (size_t)c * NN * 16;
    int off = offs[node], dg = deg[node];
    float acc[8];
#pragma unroll
    for (int q = 0; q < 8; q++) acc[q] = 0.f;
    int k = 0;
    for (; k + 8 <= dg; k += 8) {
        int s0 = csr[off + k + ng];
        int s1 = csr[off + k + 4 + ng];
        uint4 a0 = *(const uint4*)(tl + (size_t)s0 * 16 + 4 * fl);
        uint4 a1 = *(const uint4*)(tl + (size_t)s1 * 16 + 4 * fl);
        acc[0] += blo(a0.x) + blo(a1.x); acc[1] += bhi(a0.x) + bhi(a1.x);
        acc[2] += blo(a0.y) + blo(a1.y); acc[3] += bhi(a0.y) + bhi(a1.y);
        acc[4] += blo(a0.z) + blo(a1.z); acc[5] += bhi(a0.z) + bhi(a1.z);
        acc[6] += blo(a0.w) + blo(a1.w); acc[7] += bhi(a0.w) + bhi(a1.w);
    }
    if (k + 4 <= dg) {
        int s0 = csr[off + k + ng];
        uint4 a0 = *(const uint4*)(tl + (size_t)s0 * 16 + 4 * fl);
        acc[0] += blo(a0.x); acc[1] += bhi(a0.x);
        acc[2] += blo(a0.y); acc[3] += bhi(a0.y);
        acc[4] += blo(a0.z); acc[5] += bhi(a0.z);
        acc[6] += blo(a0.w); acc[7] += bhi(a0.w);
        k += 4;
    }
    if (ng < dg - k) {
        int s0 = csr[off + k + ng];
        uint4 a0 = *(const uint4*)(tl + (size_t)s0 * 16 + 4 * fl);
        acc[0] += blo(a0.x); acc[1] += bhi(a0.x);
        acc[2] += blo(a0.y); acc[3] += bhi(a0.y);
        acc[4] += blo(a0.z); acc[5] += bhi(a0.z);
        acc[6] += blo(a0.w); acc[7] += bhi(a0.w);
    }
#pragma unroll
    for (int q = 0; q < 8; q++) {
        acc[q] += __shfl_xor(acc[q], 4, 64);
        acc[q] += __shfl_xor(acc[q], 8, 64);
    }
    float s = 1.f / (float)max(dg, 1);
    u32x4 t = __builtin_nontemporal_load(
        (const u32x4*)((const uint_t*)trc + (size_t)c * NN * 16 + (size_t)node * 16 + 4 * fl));
    float v0 = fmaf(acc[0], s, blo(t.x));
    float v1 = fmaf(acc[1], s, bhi(t.x));
    float v2 = fmaf(acc[2], s, blo(t.y));
    float v3 = fmaf(acc[3], s, bhi(t.y));
    float v4 = fmaf(acc[4], s, blo(t.z));
    float v5 = fmaf(acc[5], s, bhi(t.z));
    float v6 = fmaf(acc[6], s, blo(t.w));
    float v7 = fmaf(acc[7], s, bhi(t.w));
    if (RELU) {
        v0 = fmaxf(v0, 0.f); v1 = fmaxf(v1, 0.f); v2 = fmaxf(v2, 0.f); v3 = fmaxf(v3, 0.f);
        v4 = fmaxf(v4, 0.f); v5 = fmaxf(v5, 0.f); v6 = fmaxf(v6, 0.f); v7 = fmaxf(v7, 0.f);
    }
    if (ng == 0) {
        if (OUT_BF16) {
            // next-layer input layout: [node][96] bf16
            u32x4 o;
            o.x = (uint_t)f2b(v0) | ((uint_t)f2b(v1) << 16);
            o.y = (uint_t)f2b(v2) | ((uint_t)f2b(v3) << 16);
            o.z = (uint_t)f2b(v4) | ((uint_t)f2b(v5) << 16);
            o.w = (uint_t)f2b(v6) | ((uint_t)f2b(v7) << 16);
            __builtin_nontemporal_store(
                o, (u32x4*)((uint_t*)outv + (size_t)node * (D / 2) + c * 16 + 4 * fl));
        } else {
            float* op = (float*)outv + (size_t)node * D + c * 32 + 8 * fl;
            __builtin_nontemporal_store((f32x4){v0, v1, v2, v3}, (f32x4*)op);
            __builtin_nontemporal_store((f32x4){v4, v5, v6, v7}, (f32x4*)(op + 4));
        }
    }
}

// ---------------- pool stage 1: wide-parallel run-length accumulation ----------------
// 1024 blocks x 256 thr; block = 49-node slice, thread = (feature c, row group j),
// 4 rows in flight; atomicAdd per run boundary (~512/block into 32KB accum).
// Counts are NOT accumulated here (finalize derives them by binary search).
__launch_bounds__(256) static __global__
void pool_kernel(const float* __restrict__ h, const int* __restrict__ batch,
                 float* __restrict__ accum) {
    int per = (NN + POOLB - 1) / POOLB;          // 49
    int start = blockIdx.x * per;
    int end = min(start + per, NN);
    if (start >= end) return;
    int c = threadIdx.x & 63, j = threadIdx.x >> 6;
    int i = start + j;
    if (i >= end) return;
    int gcur = batch[i];
    float acc = 0.f;
    for (; i < end; i += 4) {
        int g = batch[i];
        if (g != gcur) {
            atomicAdd(&accum[gcur * 64 + c], acc);
            acc = 0.f; gcur = g;
        }
        acc += h[(size_t)i * 64 + c];
    }
    atomicAdd(&accum[gcur * 64 + c], acc);
}

// finalize: counts via binary search on sorted batch (no atomics), divide.
__launch_bounds__(256) static __global__
void finalize_kernel(const float* __restrict__ accum, const int* __restrict__ batch,
                     float* __restrict__ out) {
    int i = blockIdx.x * 256 + threadIdx.x;
    if (i >= NG * 64) return;
    int g = i >> 6;
    int lo = 0, hi = NN;
    while (lo < hi) { int mid = (lo + hi) >> 1; if (batch[mid] < g) lo = mid + 1; else hi = mid; }
    int start = lo;
    hi = NN;
    while (lo < hi) { int mid = (lo + hi) >> 1; if (batch[mid] < g + 1) lo = mid + 1; else hi = mid; }
    int cnt = lo - start;
    out[i] = accum[i] / (float)max(cnt, 1);
}

// ---------------- launch ----------------
extern "C" void kernel_launch(void* const* d_in, const int* in_sizes, int n_in,
                              void* d_out, int out_size, void* d_ws, size_t ws_size,
                              hipStream_t stream) {
    (void)in_sizes; (void)n_in; (void)out_size; (void)ws_size;
    const float* x   = (const float*)d_in[0];
    const int*   ei  = (const int*)d_in[1];
    const int*   bat = (const int*)d_in[2];
    const float* Wl0 = (const float*)d_in[3];
    const float* b0  = (const float*)d_in[4];
    const float* Wr0 = (const float*)d_in[5];
    const float* Wl1 = (const float*)d_in[6];
    const float* b1  = (const float*)d_in[7];
    const float* Wr1 = (const float*)d_in[8];
    const float* Wl2 = (const float*)d_in[9];
    const float* b2  = (const float*)d_in[10];
    const float* Wr2 = (const float*)d_in[11];
    float* out = (float*)d_out;
    const int* src = ei;
    const int* dst = ei + NE;

    char* p = (char*)d_ws;
    auto carve = [&](size_t bytes) -> char* {
        char* r = p;
        p += (bytes + 255) & ~(size_t)255;
        return r;
    };
    int*      deg    = (int*)carve((size_t)NN * 4);
    int*      offs   = (int*)carve((size_t)NN * 4);
    int*      bucket_cnt = (int*)carve(NBKT * 4);
    uint_t*   part   = (uint_t*)carve((size_t)NBKT * BCAP * 4);
    int*      csr    = (int*)carve((size_t)NE * 4);
    float*    accum  = (float*)carve((size_t)NG * 64 * 4);
    ushort_t* xb     = (ushort_t*)carve((size_t)NP * 96 * 2);   // layer-0 input; reused as h2b
    ushort_t* h1b    = (ushort_t*)carve((size_t)NP * 96 * 2);
    ushort_t* tlc    = (ushort_t*)carve((size_t)3 * NN * 32 * 2);  // chunk-major
    ushort_t* trc    = (ushort_t*)carve((size_t)3 * NN * 32 * 2);  // chunk-major
    float*    Hf     = (float*)carve((size_t)NN * 64 * 4);

    dim3 b256(256);
    hipMemsetAsync(bucket_cnt, 0, NBKT * 4, stream);

    cvt_part_kernel<<<dim3(PARTB + CVTB), b256, 0, stream>>>(x, xb, src, dst, bucket_cnt, part, accum);
    csr_tf0_kernel<<<dim3(NBKT + TFB), b256, 0, stream>>>(part, bucket_cnt, deg, offs, csr,
                                                          xb, Wl0, b0, Wr0, tlc, trc);
    agg3_kernel<96, true, true><<<dim3(3 * AGB), b256, 0, stream>>>(tlc, trc, offs, deg, csr, h1b);
    transform_kernel<96, 12><<<dim3(TFB), b256, 0, stream>>>(h1b, Wl1, b1, Wr1, tlc, trc);
    agg3_kernel<96, true, true><<<dim3(3 * AGB), b256, 0, stream>>>(tlc, trc, offs, deg, csr, xb);
    transform_kernel<64, 8><<<dim3(TFB), b256, 0, stream>>>(xb, Wl2, b2, Wr2, tlc, trc);
    agg3_kernel<64, false, false><<<dim3(2 * AGB), b256, 0, stream>>>(tlc, trc, offs, deg, csr, Hf);
    pool_kernel<<<dim3(POOLB), b256, 0, stream>>>(Hf, bat, accum);
    finalize_kernel<<<dim3((NG * 64 + 255) / 256), b256, 0, stream>>>(accum, bat, out);
}

// Round 11
// 240.774 us; speedup vs baseline: 1.1743x; 1.0368x over previous
//
#include <hip/hip_runtime.h>
#include <stdint.h>
#include <stddef.h>

#define NN 50000
#define NP 50048            // padded rows (782 * 64) for bf16 ws buffers (MFMA A-frag OOB safe)
#define NE 800000
#define NG 128

#define NBKT 256            // dst buckets
#define NPB 196             // nodes per bucket (196*256 = 50176 >= NN)
#define BCAP 4096           // bucket capacity (mean ~3125 + 17 sigma)
#define TILE_E 3072         // edges per partition workgroup
#define PARTB 261           // ceil(NE / TILE_E)
#define AGB 3125            // agg blocks per chunk (3125 * 16 nodes = 50000)
#define TFB 782             // transform blocks (NP/64)

typedef __attribute__((ext_vector_type(8))) short bf16x8;
typedef __attribute__((ext_vector_type(4))) float f32x4;
typedef __attribute__((ext_vector_type(4))) unsigned int u32x4;
typedef unsigned short ushort_t;
typedef unsigned int uint_t;

// float -> bf16 (RNE) and bf16x2 unpack helpers
static __device__ inline ushort_t f2b(float f) {
    union { float f; uint_t u; } v; v.f = f;
    uint_t r = v.u + 0x7FFFu + ((v.u >> 16) & 1u);
    return (ushort_t)(r >> 16);
}
static __device__ inline float blo(uint_t u) {
    union { uint_t u; float f; } v; v.u = u << 16; return v.f;
}
static __device__ inline float bhi(uint_t u) {
    union { uint_t u; float f; } v; v.u = u & 0xFFFF0000u; return v.f;
}

// ---------------- K1: partition (blocks 0..PARTB-1) + zero accum (rest) --------
__launch_bounds__(256) static __global__
void part_zero_kernel(const int* __restrict__ src, const int* __restrict__ dst,
                      int* __restrict__ bucket_cnt, uint_t* __restrict__ part,
                      float* __restrict__ accum) {
    __shared__ int hist[NBKT];
    int tid = threadIdx.x;
    if (blockIdx.x < PARTB) {
        // two-pass partition: no per-thread arrays -> no scratch spill (R7)
        hist[tid] = 0;
        __syncthreads();
        int base = blockIdx.x * TILE_E;
        int end = min(base + TILE_E, NE);
        for (int i = base + tid; i < end; i += 256)
            atomicAdd(&hist[dst[i] / NPB], 1);
        __syncthreads();
        int r = atomicAdd(&bucket_cnt[tid], hist[tid]);   // reserve
        __syncthreads();
        hist[tid] = r;                                    // reuse as cursor
        __syncthreads();
        for (int i = base + tid; i < end; i += 256) {
            int s = src[i], d = dst[i];
            int b = d / NPB;
            int dl = d - b * NPB;
            int p = atomicAdd(&hist[b], 1);
            part[b * BCAP + p] = ((uint_t)dl << 16) | (uint_t)s;
        }
    } else {
        int gid = (blockIdx.x - PARTB) * 256 + tid;
        if (gid < NG * 64) accum[gid] = 0.f;
    }
}

// ---------------- csr_build body (per-bucket CSR + deg + offs) ----------------
static __device__ void csr_build_body(int b, char* smem, const uint_t* __restrict__ part,
                                      const int* __restrict__ bucket_cnt, int* __restrict__ deg,
                                      int* __restrict__ offs, int* __restrict__ csr) {
    uint_t* stage = (uint_t*)smem;                       // 16384 B
    ushort_t* cstage = (ushort_t*)(smem + 16384);        // 8192 B
    int* cnt_s = (int*)(smem + 24576);                   // 1024 B
    int* scan_l = (int*)(smem + 25600);                  // 1024 B
    int* cur_l = (int*)(smem + 26624);                   // 1024 B
    int tid = threadIdx.x;
    int bc = bucket_cnt[tid];
    cnt_s[tid] = bc;
    scan_l[tid] = bc;
    __syncthreads();
    for (int off = 1; off < NBKT; off <<= 1) {
        int t = (tid >= off) ? scan_l[tid - off] : 0;
        __syncthreads();
        scan_l[tid] += t;
        __syncthreads();
    }
    int base = scan_l[b] - cnt_s[b];
    int n = cnt_s[b];
    __syncthreads();
    cnt_s[tid] = 0;                           // reuse as deg_l
    __syncthreads();
    for (int i = tid; i < n; i += 256) {
        uint_t e = part[(size_t)b * BCAP + i];
        stage[i] = e;
        atomicAdd(&cnt_s[e >> 16], 1);
    }
    __syncthreads();
    int v = cnt_s[tid];
    scan_l[tid] = v;
    __syncthreads();
    for (int off = 1; off < NBKT; off <<= 1) {
        int t = (tid >= off) ? scan_l[tid - off] : 0;
        __syncthreads();
        scan_l[tid] += t;
        __syncthreads();
    }
    int ex = scan_l[tid] - v;
    scan_l[tid] = ex;
    cur_l[tid] = 0;
    __syncthreads();
    int g = b * NPB + tid;
    if (tid < NPB && g < NN) { deg[g] = v; offs[g] = base + ex; }
    for (int i = tid; i < n; i += 256) {
        uint_t e = stage[i];
        int dl = e >> 16;
        int p = atomicAdd(&cur_l[dl], 1);
        cstage[scan_l[dl] + p] = (ushort_t)(e & 0xFFFFu);
    }
    __syncthreads();
    for (int i = tid; i < n; i += 256) csr[base + i] = (int)cstage[i];
}

// ---------------- MFMA transform body (chunk-major outputs) ----------------
// FP32_IN: layer 0 reads x (fp32) directly, converts to A-frags in-register
// (kills the xb staging write+read; rows >= NN clamp to NN-1 — values unused,
// C-write guards node < NN). Outputs chunk-major: tlc[(c*NN+node)*32+f].
template <int DOUT, int NT, bool FP32_IN>   // OT = 2*DOUT = NT*16, DIN = 96
static __device__ void transform_body(int bid, char* smem,
                                      const void* __restrict__ hin, const float* __restrict__ Wl,
                                      const float* __restrict__ bias, const float* __restrict__ Wr,
                                      ushort_t* __restrict__ tlc, ushort_t* __restrict__ trc) {
    constexpr int DIN = 96;
    short* w_s = (short*)smem;                // NT*3*64*8 shorts (<= 36864 B)
    int tid = threadIdx.x;
    for (int idx = tid; idx < NT * 3 * 64; idx += 256) {
        int ci = idx >> 6, ln = idx & 63;
        int t = ci / 3, s = ci - 3 * t;
        int o = t * 16 + (ln & 15);
        int c0 = s * 32 + (ln >> 4) * 8;
        const float* wrow = (o < DOUT) ? (Wl + (size_t)o * DIN)
                                       : (Wr + (size_t)(o - DOUT) * DIN);
        float4 v0 = *(const float4*)(wrow + c0);
        float4 v1 = *(const float4*)(wrow + c0 + 4);
        bf16x8 pk;
        pk[0] = (short)f2b(v0.x); pk[1] = (short)f2b(v0.y);
        pk[2] = (short)f2b(v0.z); pk[3] = (short)f2b(v0.w);
        pk[4] = (short)f2b(v1.x); pk[5] = (short)f2b(v1.y);
        pk[6] = (short)f2b(v1.z); pk[7] = (short)f2b(v1.w);
        *(bf16x8*)&w_s[idx * 8] = pk;
    }
    int lane = tid & 63;
    int m0 = bid * 64 + (tid >> 6) * 16;
    int row = m0 + (lane & 15);
    bf16x8 a0, a1, a2;
    if (FP32_IN) {
        const float* xr = (const float*)hin + (size_t)min(row, NN - 1) * DIN + (lane >> 4) * 8;
#pragma unroll
        for (int s = 0; s < 3; s++) {
            float4 v0 = *(const float4*)(xr + s * 32);
            float4 v1 = *(const float4*)(xr + s * 32 + 4);
            bf16x8 pk;
            pk[0] = (short)f2b(v0.x); pk[1] = (short)f2b(v0.y);
            pk[2] = (short)f2b(v0.z); pk[3] = (short)f2b(v0.w);
            pk[4] = (short)f2b(v1.x); pk[5] = (short)f2b(v1.y);
            pk[6] = (short)f2b(v1.z); pk[7] = (short)f2b(v1.w);
            if (s == 0) a0 = pk; else if (s == 1) a1 = pk; else a2 = pk;
        }
    } else {
        const bf16x8* arow = (const bf16x8*)((const ushort_t*)hin + (size_t)row * DIN) + (lane >> 4);
        a0 = arow[0];
        a1 = arow[4];
        a2 = arow[8];
    }
    __syncthreads();
    const bf16x8* wp = (const bf16x8*)w_s + lane;
    f32x4 acc[NT];
#pragma unroll
    for (int t = 0; t < NT; t++) {
        acc[t] = (f32x4){0.f, 0.f, 0.f, 0.f};
        acc[t] = __builtin_amdgcn_mfma_f32_16x16x32_bf16(a0, wp[(t * 3 + 0) * 64], acc[t], 0, 0, 0);
        acc[t] = __builtin_amdgcn_mfma_f32_16x16x32_bf16(a1, wp[(t * 3 + 1) * 64], acc[t], 0, 0, 0);
        acc[t] = __builtin_amdgcn_mfma_f32_16x16x32_bf16(a2, wp[(t * 3 + 2) * 64], acc[t], 0, 0, 0);
    }
    int quad = lane >> 4, col = lane & 15;
#pragma unroll
    for (int t = 0; t < NT; t++) {
        int o = t * 16 + col;
        bool is_r = (o >= DOUT);
        float bv = is_r ? bias[o - DOUT] : 0.f;
        ushort_t* outp = is_r ? trc : tlc;
        int oo = is_r ? (o - DOUT) : o;
        int cch = oo >> 5, f = oo & 31;
        ushort_t* ob = outp + ((size_t)cch * NN) * 32 + f;
#pragma unroll
        for (int r = 0; r < 4; r++) {
            int node = m0 + quad * 4 + r;
            if (node < NN) ob[(size_t)node * 32] = f2b(acc[t][r] + bv);
        }
    }
}

// ---------------- K2: csr_build (blocks 0..255) + transform layer0 (rest) ----------------
__launch_bounds__(256) static __global__
void csr_tf0_kernel(const uint_t* __restrict__ part, const int* __restrict__ bucket_cnt,
                    int* __restrict__ deg, int* __restrict__ offs, int* __restrict__ csr,
                    const float* __restrict__ x, const float* __restrict__ Wl0,
                    const float* __restrict__ b0, const float* __restrict__ Wr0,
                    ushort_t* __restrict__ tlc, ushort_t* __restrict__ trc) {
    __shared__ __align__(16) char smem[36864];
    if (blockIdx.x < NBKT)
        csr_build_body(blockIdx.x, smem, part, bucket_cnt, deg, offs, csr);
    else
        transform_body<96, 12, true>(blockIdx.x - NBKT, smem, x, Wl0, b0, Wr0, tlc, trc);
}

// standalone transform (layers 1,2; bf16 input from ws)
template <int DOUT, int NT>
__launch_bounds__(256, 4) static __global__
void transform_kernel(const ushort_t* __restrict__ hb, const float* __restrict__ Wl,
                      const float* __restrict__ bias, const float* __restrict__ Wr,
                      ushort_t* __restrict__ tlc, ushort_t* __restrict__ trc) {
    __shared__ __align__(16) char smem[NT * 3 * 64 * 8 * 2];
    transform_body<DOUT, NT, false>(blockIdx.x, smem, hb, Wl, bias, Wr, tlc, trc);
}

// ---------------- chunked aggregation (layers 0,1 -> bf16 next-layer input) -----------
// One 32-feature chunk per grid segment; gather set = 3.2 MB (L2-sized); tr/out
// streams nontemporal. 16 lanes/node = 4 neighbor-groups x 4 feature-lanes;
// one dwordx4/lane covers the 64B row; shfl_xor(4,8) cross-group reduce.
template <int D>
__launch_bounds__(256) static __global__
void agg3_kernel(const ushort_t* __restrict__ tlc, const ushort_t* __restrict__ trc,
                 const int* __restrict__ offs, const int* __restrict__ deg,
                 const int* __restrict__ csr, ushort_t* __restrict__ outb) {
    int bx = blockIdx.x;
    int c = bx / AGB;
    int b = bx - c * AGB;
    int tid = threadIdx.x;
    int node = b * 16 + (tid >> 4);
    int lane = tid & 15;
    int ng = lane >> 2, fl = lane & 3;
    const uint_t* tl = (const uint_t*)tlc + (size_t)c * NN * 16;
    int off = offs[node], dg = deg[node];
    float acc[8];
#pragma unroll
    for (int q = 0; q < 8; q++) acc[q] = 0.f;
    int k = 0;
    for (; k + 8 <= dg; k += 8) {
        int s0 = csr[off + k + ng];
        int s1 = csr[off + k + 4 + ng];
        uint4 a0 = *(const uint4*)(tl + (size_t)s0 * 16 + 4 * fl);
        uint4 a1 = *(const uint4*)(tl + (size_t)s1 * 16 + 4 * fl);
        acc[0] += blo(a0.x) + blo(a1.x); acc[1] += bhi(a0.x) + bhi(a1.x);
        acc[2] += blo(a0.y) + blo(a1.y); acc[3] += bhi(a0.y) + bhi(a1.y);
        acc[4] += blo(a0.z) + blo(a1.z); acc[5] += bhi(a0.z) + bhi(a1.z);
        acc[6] += blo(a0.w) + blo(a1.w); acc[7] += bhi(a0.w) + bhi(a1.w);
    }
    if (k + 4 <= dg) {
        int s0 = csr[off + k + ng];
        uint4 a0 = *(const uint4*)(tl + (size_t)s0 * 16 + 4 * fl);
        acc[0] += blo(a0.x); acc[1] += bhi(a0.x);
        acc[2] += blo(a0.y); acc[3] += bhi(a0.y);
        acc[4] += blo(a0.z); acc[5] += bhi(a0.z);
        acc[6] += blo(a0.w); acc[7] += bhi(a0.w);
        k += 4;
    }
    if (ng < dg - k) {
        int s0 = csr[off + k + ng];
        uint4 a0 = *(const uint4*)(tl + (size_t)s0 * 16 + 4 * fl);
        acc[0] += blo(a0.x); acc[1] += bhi(a0.x);
        acc[2] += blo(a0.y); acc[3] += bhi(a0.y);
        acc[4] += blo(a0.z); acc[5] += bhi(a0.z);
        acc[6] += blo(a0.w); acc[7] += bhi(a0.w);
    }
#pragma unroll
    for (int q = 0; q < 8; q++) {
        acc[q] += __shfl_xor(acc[q], 4, 64);
        acc[q] += __shfl_xor(acc[q], 8, 64);
    }
    float s = 1.f / (float)max(dg, 1);
    u32x4 t = __builtin_nontemporal_load(
        (const u32x4*)((const uint_t*)trc + (size_t)c * NN * 16 + (size_t)node * 16 + 4 * fl));
    float v0 = fmaxf(fmaf(acc[0], s, blo(t.x)), 0.f);
    float v1 = fmaxf(fmaf(acc[1], s, bhi(t.x)), 0.f);
    float v2 = fmaxf(fmaf(acc[2], s, blo(t.y)), 0.f);
    float v3 = fmaxf(fmaf(acc[3], s, bhi(t.y)), 0.f);
    float v4 = fmaxf(fmaf(acc[4], s, blo(t.z)), 0.f);
    float v5 = fmaxf(fmaf(acc[5], s, bhi(t.z)), 0.f);
    float v6 = fmaxf(fmaf(acc[6], s, blo(t.w)), 0.f);
    float v7 = fmaxf(fmaf(acc[7], s, bhi(t.w)), 0.f);
    if (ng == 0) {
        u32x4 o;
        o.x = (uint_t)f2b(v0) | ((uint_t)f2b(v1) << 16);
        o.y = (uint_t)f2b(v2) | ((uint_t)f2b(v3) << 16);
        o.z = (uint_t)f2b(v4) | ((uint_t)f2b(v5) << 16);
        o.w = (uint_t)f2b(v6) | ((uint_t)f2b(v7) << 16);
        __builtin_nontemporal_store(
            o, (u32x4*)((uint_t*)outb + (size_t)node * (D / 2) + c * 16 + 4 * fl));
    }
}

// ---------------- final agg + pool fused (D=64, no relu) ----------------
// Block's 16 nodes are contiguous and batch is sorted -> block spans 1-2
// graphs. Stage 16x32 fp32 in LDS, 32 walker threads run-length reduce by
// graph id, ~33 atomics/block into the 32KB L2-resident accum. Kills Hf
// (25.6 MB traffic) + the pool dispatch.
__launch_bounds__(256) static __global__
void agg_pool_kernel(const ushort_t* __restrict__ tlc, const ushort_t* __restrict__ trc,
                     const int* __restrict__ offs, const int* __restrict__ deg,
                     const int* __restrict__ csr, const int* __restrict__ batch,
                     float* __restrict__ accum) {
    __shared__ float hsum[16][32];
    __shared__ int gids[16];
    int bx = blockIdx.x;
    int c = bx / AGB;
    int b = bx - c * AGB;
    int tid = threadIdx.x;
    int nl = tid >> 4;
    int node = b * 16 + nl;
    int lane = tid & 15;
    int ng = lane >> 2, fl = lane & 3;
    if (tid < 16) gids[tid] = batch[b * 16 + tid];
    const uint_t* tl = (const uint_t*)tlc + (size_t)c * NN * 16;
    int off = offs[node], dg = deg[node];
    float acc[8];
#pragma unroll
    for (int q = 0; q < 8; q++) acc[q] = 0.f;
    int k = 0;
    for (; k + 8 <= dg; k += 8) {
        int s0 = csr[off + k + ng];
        int s1 = csr[off + k + 4 + ng];
        uint4 a0 = *(const uint4*)(tl + (size_t)s0 * 16 + 4 * fl);
        uint4 a1 = *(const uint4*)(tl + (size_t)s1 * 16 + 4 * fl);
        acc[0] += blo(a0.x) + blo(a1.x); acc[1] += bhi(a0.x) + bhi(a1.x);
        acc[2] += blo(a0.y) + blo(a1.y); acc[3] += bhi(a0.y) + bhi(a1.y);
        acc[4] += blo(a0.z) + blo(a1.z); acc[5] += bhi(a0.z) + bhi(a1.z);
        acc[6] += blo(a0.w) + blo(a1.w); acc[7] += bhi(a0.w) + bhi(a1.w);
    }
    if (k + 4 <= dg) {
        int s0 = csr[off + k + ng];
        uint4 a0 = *(const uint4*)(tl + (size_t)s0 * 16 + 4 * fl);
        acc[0] += blo(a0.x); acc[1] += bhi(a0.x);
        acc[2] += blo(a0.y); acc[3] += bhi(a0.y);
        acc[4] += blo(a0.z); acc[5] += bhi(a0.z);
        acc[6] += blo(a0.w); acc[7] += bhi(a0.w);
        k += 4;
    }
    if (ng < dg - k) {
        int s0 = csr[off + k + ng];
        uint4 a0 = *(const uint4*)(tl + (size_t)s0 * 16 + 4 * fl);
        acc[0] += blo(a0.x); acc[1] += bhi(a0.x);
        acc[2] += blo(a0.y); acc[3] += bhi(a0.y);
        acc[4] += blo(a0.z); acc[5] += bhi(a0.z);
        acc[6] += blo(a0.w); acc[7] += bhi(a0.w);
    }
#pragma unroll
    for (int q = 0; q < 8; q++) {
        acc[q] += __shfl_xor(acc[q], 4, 64);
        acc[q] += __shfl_xor(acc[q], 8, 64);
    }
    float s = 1.f / (float)max(dg, 1);
    u32x4 t = __builtin_nontemporal_load(
        (const u32x4*)((const uint_t*)trc + (size_t)c * NN * 16 + (size_t)node * 16 + 4 * fl));
    if (ng == 0) {
        hsum[nl][8 * fl + 0] = fmaf(acc[0], s, blo(t.x));
        hsum[nl][8 * fl + 1] = fmaf(acc[1], s, bhi(t.x));
        hsum[nl][8 * fl + 2] = fmaf(acc[2], s, blo(t.y));
        hsum[nl][8 * fl + 3] = fmaf(acc[3], s, bhi(t.y));
        hsum[nl][8 * fl + 4] = fmaf(acc[4], s, blo(t.z));
        hsum[nl][8 * fl + 5] = fmaf(acc[5], s, bhi(t.z));
        hsum[nl][8 * fl + 6] = fmaf(acc[6], s, blo(t.w));
        hsum[nl][8 * fl + 7] = fmaf(acc[7], s, bhi(t.w));
    }
    __syncthreads();
    if (tid < 32) {
        int gcur = gids[0];
        float ps = 0.f;
        for (int j = 0; j < 16; j++) {
            int g = gids[j];
            if (g != gcur) {
                atomicAdd(&accum[gcur * 64 + c * 32 + tid], ps);
                ps = 0.f; gcur = g;
            }
            ps += hsum[j][tid];
        }
        atomicAdd(&accum[gcur * 64 + c * 32 + tid], ps);
    }
}

// finalize: counts via binary search on sorted batch (no atomics), divide.
__launch_bounds__(256) static __global__
void finalize_kernel(const float* __restrict__ accum, const int* __restrict__ batch,
                     float* __restrict__ out) {
    int i = blockIdx.x * 256 + threadIdx.x;
    if (i >= NG * 64) return;
    int g = i >> 6;
    int lo = 0, hi = NN;
    while (lo < hi) { int mid = (lo + hi) >> 1; if (batch[mid] < g) lo = mid + 1; else hi = mid; }
    int start = lo;
    hi = NN;
    while (lo < hi) { int mid = (lo + hi) >> 1; if (batch[mid] < g + 1) lo = mid + 1; else hi = mid; }
    int cnt = lo - start;
    out[i] = accum[i] / (float)max(cnt, 1);
}

// ---------------- launch ----------------
extern "C" void kernel_launch(void* const* d_in, const int* in_sizes, int n_in,
                              void* d_out, int out_size, void* d_ws, size_t ws_size,
                              hipStream_t stream) {
    (void)in_sizes; (void)n_in; (void)out_size; (void)ws_size;
    const float* x   = (const float*)d_in[0];
    const int*   ei  = (const int*)d_in[1];
    const int*   bat = (const int*)d_in[2];
    const float* Wl0 = (const float*)d_in[3];
    const float* b0  = (const float*)d_in[4];
    const float* Wr0 = (const float*)d_in[5];
    const float* Wl1 = (const float*)d_in[6];
    const float* b1  = (const float*)d_in[7];
    const float* Wr1 = (const float*)d_in[8];
    const float* Wl2 = (const float*)d_in[9];
    const float* b2  = (const float*)d_in[10];
    const float* Wr2 = (const float*)d_in[11];
    float* out = (float*)d_out;
    const int* src = ei;
    const int* dst = ei + NE;

    char* p = (char*)d_ws;
    auto carve = [&](size_t bytes) -> char* {
        char* r = p;
        p += (bytes + 255) & ~(size_t)255;
        return r;
    };
    int*      deg    = (int*)carve((size_t)NN * 4);
    int*      offs   = (int*)carve((size_t)NN * 4);
    int*      bucket_cnt = (int*)carve(NBKT * 4);
    uint_t*   part   = (uint_t*)carve((size_t)NBKT * BCAP * 4);
    int*      csr    = (int*)carve((size_t)NE * 4);
    float*    accum  = (float*)carve((size_t)NG * 64 * 4);
    ushort_t* h1b    = (ushort_t*)carve((size_t)NP * 96 * 2);   // layer-1 input
    ushort_t* h2b    = (ushort_t*)carve((size_t)NP * 96 * 2);   // layer-2 input
    ushort_t* tlc    = (ushort_t*)carve((size_t)3 * NN * 32 * 2);  // chunk-major
    ushort_t* trc    = (ushort_t*)carve((size_t)3 * NN * 32 * 2);  // chunk-major

    dim3 b256(256);
    hipMemsetAsync(bucket_cnt, 0, NBKT * 4, stream);

    part_zero_kernel<<<dim3(PARTB + 32), b256, 0, stream>>>(src, dst, bucket_cnt, part, accum);
    csr_tf0_kernel<<<dim3(NBKT + TFB), b256, 0, stream>>>(part, bucket_cnt, deg, offs, csr,
                                                          x, Wl0, b0, Wr0, tlc, trc);
    agg3_kernel<96><<<dim3(3 * AGB), b256, 0, stream>>>(tlc, trc, offs, deg, csr, h1b);
    transform_kernel<96, 12><<<dim3(TFB), b256, 0, stream>>>(h1b, Wl1, b1, Wr1, tlc, trc);
    agg3_kernel<96><<<dim3(3 * AGB), b256, 0, stream>>>(tlc, trc, offs, deg, csr, h2b);
    transform_kernel<64, 8><<<dim3(TFB), b256, 0, stream>>>(h2b, Wl2, b2, Wr2, tlc, trc);
    agg_pool_kernel<<<dim3(2 * AGB), b256, 0, stream>>>(tlc, trc, offs, deg, csr, bat, accum);
    finalize_kernel<<<dim3((NG * 64 + 255) / 256), b256, 0, stream>>>(accum, bat, out);
}

// Round 12
// 237.021 us; speedup vs baseline: 1.1929x; 1.0158x over previous
//
#include <hip/hip_runtime.h>
#include <stdint.h>
#include <stddef.h>

#define NN 50000
#define NP 50048            // padded rows (782 * 64) for bf16 ws buffers (MFMA A-frag OOB safe)
#define NE 800000
#define NG 128

#define NBKT 256            // dst buckets
#define NPB 196             // nodes per bucket (196*256 = 50176 >= NN)
#define BCAP 4096           // bucket capacity (mean ~3125 + 17 sigma)
#define TILE_E 1536         // edges per partition workgroup (521 blocks ~ 2/CU)
#define PARTB 521           // ceil(NE / TILE_E)
#define AGB 3125            // agg blocks per chunk (3125 * 16 nodes = 50000)
#define TFB 782             // transform blocks (NP/64)

typedef __attribute__((ext_vector_type(8))) short bf16x8;
typedef __attribute__((ext_vector_type(4))) float f32x4;
typedef __attribute__((ext_vector_type(4))) unsigned int u32x4;
typedef unsigned short ushort_t;
typedef unsigned int uint_t;

// float -> bf16 (RNE) and bf16x2 unpack helpers
static __device__ inline ushort_t f2b(float f) {
    union { float f; uint_t u; } v; v.f = f;
    uint_t r = v.u + 0x7FFFu + ((v.u >> 16) & 1u);
    return (ushort_t)(r >> 16);
}
static __device__ inline float blo(uint_t u) {
    union { uint_t u; float f; } v; v.u = u << 16; return v.f;
}
static __device__ inline float bhi(uint_t u) {
    union { uint_t u; float f; } v; v.u = u & 0xFFFF0000u; return v.f;
}

// ---------------- K1: partition (blocks 0..PARTB-1) + zero out + inv_cnt (rest) --------
__launch_bounds__(256) static __global__
void part_zero_kernel(const int* __restrict__ src, const int* __restrict__ dst,
                      int* __restrict__ bucket_cnt, uint_t* __restrict__ part,
                      float* __restrict__ out, const int* __restrict__ batch,
                      float* __restrict__ inv_cnt) {
    __shared__ int hist[NBKT];
    int tid = threadIdx.x;
    if (blockIdx.x < PARTB) {
        // two-pass partition: no per-thread arrays -> no scratch spill (R7)
        hist[tid] = 0;
        __syncthreads();
        int base = blockIdx.x * TILE_E;
        int end = min(base + TILE_E, NE);
        for (int i = base + tid; i < end; i += 256)
            atomicAdd(&hist[dst[i] / NPB], 1);
        __syncthreads();
        int r = atomicAdd(&bucket_cnt[tid], hist[tid]);   // reserve
        __syncthreads();
        hist[tid] = r;                                    // reuse as cursor
        __syncthreads();
        for (int i = base + tid; i < end; i += 256) {
            int s = src[i], d = dst[i];
            int b = d / NPB;
            int dl = d - b * NPB;
            int p = atomicAdd(&hist[b], 1);
            part[b * BCAP + p] = ((uint_t)dl << 16) | (uint_t)s;
        }
    } else {
        int gid = (blockIdx.x - PARTB) * 256 + tid;
        if (gid < NG * 64) out[gid] = 0.f;                // d_out is 0xAA-poisoned
        if (gid < NG) {
            int g = gid;
            int lo = 0, hi = NN;
            while (lo < hi) { int m = (lo + hi) >> 1; if (batch[m] < g) lo = m + 1; else hi = m; }
            int start = lo;
            hi = NN;
            while (lo < hi) { int m = (lo + hi) >> 1; if (batch[m] < g + 1) lo = m + 1; else hi = m; }
            inv_cnt[g] = 1.f / (float)max(lo - start, 1);
        }
    }
}

// ---------------- csr_build body (per-bucket CSR + deg + offs) ----------------
static __device__ void csr_build_body(int b, char* smem, const uint_t* __restrict__ part,
                                      const int* __restrict__ bucket_cnt, int* __restrict__ deg,
                                      int* __restrict__ offs, int* __restrict__ csr) {
    uint_t* stage = (uint_t*)smem;                       // 16384 B
    ushort_t* cstage = (ushort_t*)(smem + 16384);        // 8192 B
    int* cnt_s = (int*)(smem + 24576);                   // 1024 B
    int* scan_l = (int*)(smem + 25600);                  // 1024 B
    int* cur_l = (int*)(smem + 26624);                   // 1024 B
    int tid = threadIdx.x;
    int bc = bucket_cnt[tid];
    cnt_s[tid] = bc;
    scan_l[tid] = bc;
    __syncthreads();
    for (int off = 1; off < NBKT; off <<= 1) {
        int t = (tid >= off) ? scan_l[tid - off] : 0;
        __syncthreads();
        scan_l[tid] += t;
        __syncthreads();
    }
    int base = scan_l[b] - cnt_s[b];
    int n = cnt_s[b];
    __syncthreads();
    cnt_s[tid] = 0;                           // reuse as deg_l
    __syncthreads();
    for (int i = tid; i < n; i += 256) {
        uint_t e = part[(size_t)b * BCAP + i];
        stage[i] = e;
        atomicAdd(&cnt_s[e >> 16], 1);
    }
    __syncthreads();
    int v = cnt_s[tid];
    scan_l[tid] = v;
    __syncthreads();
    for (int off = 1; off < NBKT; off <<= 1) {
        int t = (tid >= off) ? scan_l[tid - off] : 0;
        __syncthreads();
        scan_l[tid] += t;
        __syncthreads();
    }
    int ex = scan_l[tid] - v;
    scan_l[tid] = ex;
    cur_l[tid] = 0;
    __syncthreads();
    int g = b * NPB + tid;
    if (tid < NPB && g < NN) { deg[g] = v; offs[g] = base + ex; }
    for (int i = tid; i < n; i += 256) {
        uint_t e = stage[i];
        int dl = e >> 16;
        int p = atomicAdd(&cur_l[dl], 1);
        cstage[scan_l[dl] + p] = (ushort_t)(e & 0xFFFFu);
    }
    __syncthreads();
    for (int i = tid; i < n; i += 256) csr[base + i] = (int)cstage[i];
}

// ---------------- MFMA transform body (chunk-major outputs) ----------------
// FP32_IN: layer 0 reads x (fp32) directly, converts to A-frags in-register.
// Outputs chunk-major: tlc[(c*NN+node)*32+f], c = o>>5, f = o&31.
template <int DOUT, int NT, bool FP32_IN>   // OT = 2*DOUT = NT*16, DIN = 96
static __device__ void transform_body(int bid, char* smem,
                                      const void* __restrict__ hin, const float* __restrict__ Wl,
                                      const float* __restrict__ bias, const float* __restrict__ Wr,
                                      ushort_t* __restrict__ tlc, ushort_t* __restrict__ trc) {
    constexpr int DIN = 96;
    short* w_s = (short*)smem;                // NT*3*64*8 shorts (<= 36864 B)
    int tid = threadIdx.x;
    for (int idx = tid; idx < NT * 3 * 64; idx += 256) {
        int ci = idx >> 6, ln = idx & 63;
        int t = ci / 3, s = ci - 3 * t;
        int o = t * 16 + (ln & 15);
        int c0 = s * 32 + (ln >> 4) * 8;
        const float* wrow = (o < DOUT) ? (Wl + (size_t)o * DIN)
                                       : (Wr + (size_t)(o - DOUT) * DIN);
        float4 v0 = *(const float4*)(wrow + c0);
        float4 v1 = *(const float4*)(wrow + c0 + 4);
        bf16x8 pk;
        pk[0] = (short)f2b(v0.x); pk[1] = (short)f2b(v0.y);
        pk[2] = (short)f2b(v0.z); pk[3] = (short)f2b(v0.w);
        pk[4] = (short)f2b(v1.x); pk[5] = (short)f2b(v1.y);
        pk[6] = (short)f2b(v1.z); pk[7] = (short)f2b(v1.w);
        *(bf16x8*)&w_s[idx * 8] = pk;
    }
    int lane = tid & 63;
    int m0 = bid * 64 + (tid >> 6) * 16;
    int row = m0 + (lane & 15);
    bf16x8 a0, a1, a2;
    if (FP32_IN) {
        const float* xr = (const float*)hin + (size_t)min(row, NN - 1) * DIN + (lane >> 4) * 8;
#pragma unroll
        for (int s = 0; s < 3; s++) {
            float4 v0 = *(const float4*)(xr + s * 32);
            float4 v1 = *(const float4*)(xr + s * 32 + 4);
            bf16x8 pk;
            pk[0] = (short)f2b(v0.x); pk[1] = (short)f2b(v0.y);
            pk[2] = (short)f2b(v0.z); pk[3] = (short)f2b(v0.w);
            pk[4] = (short)f2b(v1.x); pk[5] = (short)f2b(v1.y);
            pk[6] = (short)f2b(v1.z); pk[7] = (short)f2b(v1.w);
            if (s == 0) a0 = pk; else if (s == 1) a1 = pk; else a2 = pk;
        }
    } else {
        const bf16x8* arow = (const bf16x8*)((const ushort_t*)hin + (size_t)row * DIN) + (lane >> 4);
        a0 = arow[0];
        a1 = arow[4];
        a2 = arow[8];
    }
    __syncthreads();
    const bf16x8* wp = (const bf16x8*)w_s + lane;
    f32x4 acc[NT];
#pragma unroll
    for (int t = 0; t < NT; t++) {
        acc[t] = (f32x4){0.f, 0.f, 0.f, 0.f};
        acc[t] = __builtin_amdgcn_mfma_f32_16x16x32_bf16(a0, wp[(t * 3 + 0) * 64], acc[t], 0, 0, 0);
        acc[t] = __builtin_amdgcn_mfma_f32_16x16x32_bf16(a1, wp[(t * 3 + 1) * 64], acc[t], 0, 0, 0);
        acc[t] = __builtin_amdgcn_mfma_f32_16x16x32_bf16(a2, wp[(t * 3 + 2) * 64], acc[t], 0, 0, 0);
    }
    int quad = lane >> 4, col = lane & 15;
#pragma unroll
    for (int t = 0; t < NT; t++) {
        int o = t * 16 + col;
        bool is_r = (o >= DOUT);
        float bv = is_r ? bias[o - DOUT] : 0.f;
        ushort_t* outp = is_r ? trc : tlc;
        int oo = is_r ? (o - DOUT) : o;
        int cch = oo >> 5, f = oo & 31;
        ushort_t* ob = outp + ((size_t)cch * NN) * 32 + f;
#pragma unroll
        for (int r = 0; r < 4; r++) {
            int node = m0 + quad * 4 + r;
            if (node < NN) ob[(size_t)node * 32] = f2b(acc[t][r] + bv);
        }
    }
}

// ---------------- K2: csr_build (blocks 0..255) + transform layer0 (rest) ----------------
__launch_bounds__(256) static __global__
void csr_tf0_kernel(const uint_t* __restrict__ part, const int* __restrict__ bucket_cnt,
                    int* __restrict__ deg, int* __restrict__ offs, int* __restrict__ csr,
                    const float* __restrict__ x, const float* __restrict__ Wl0,
                    const float* __restrict__ b0, const float* __restrict__ Wr0,
                    ushort_t* __restrict__ tlc, ushort_t* __restrict__ trc) {
    __shared__ __align__(16) char smem[36864];
    if (blockIdx.x < NBKT)
        csr_build_body(blockIdx.x, smem, part, bucket_cnt, deg, offs, csr);
    else
        transform_body<96, 12, true>(blockIdx.x - NBKT, smem, x, Wl0, b0, Wr0, tlc, trc);
}

// standalone transform (layers 1,2; bf16 input from ws)
template <int DOUT, int NT>
__launch_bounds__(256, 4) static __global__
void transform_kernel(const ushort_t* __restrict__ hb, const float* __restrict__ Wl,
                      const float* __restrict__ bias, const float* __restrict__ Wr,
                      ushort_t* __restrict__ tlc, ushort_t* __restrict__ trc) {
    __shared__ __align__(16) char smem[NT * 3 * 64 * 8 * 2];
    transform_body<DOUT, NT, false>(blockIdx.x, smem, hb, Wl, bias, Wr, tlc, trc);
}

// ---------------- gather inner loop (shared by agg3 / agg_pool) ----------------
// 16-deep tier (4 row loads in flight; mean deg 16 -> one iteration), then 8/4/tail.
static __device__ inline void gather_accum(const uint_t* __restrict__ tl,
                                           const int* __restrict__ csr,
                                           int off, int dg, int ng, int fl,
                                           float* __restrict__ acc) {
    int k = 0;
    for (; k + 16 <= dg; k += 16) {
        int s0 = csr[off + k + ng];
        int s1 = csr[off + k + 4 + ng];
        int s2 = csr[off + k + 8 + ng];
        int s3 = csr[off + k + 12 + ng];
        uint4 a0 = *(const uint4*)(tl + (size_t)s0 * 16 + 4 * fl);
        uint4 a1 = *(const uint4*)(tl + (size_t)s1 * 16 + 4 * fl);
        uint4 a2 = *(const uint4*)(tl + (size_t)s2 * 16 + 4 * fl);
        uint4 a3 = *(const uint4*)(tl + (size_t)s3 * 16 + 4 * fl);
        acc[0] += (blo(a0.x) + blo(a1.x)) + (blo(a2.x) + blo(a3.x));
        acc[1] += (bhi(a0.x) + bhi(a1.x)) + (bhi(a2.x) + bhi(a3.x));
        acc[2] += (blo(a0.y) + blo(a1.y)) + (blo(a2.y) + blo(a3.y));
        acc[3] += (bhi(a0.y) + bhi(a1.y)) + (bhi(a2.y) + bhi(a3.y));
        acc[4] += (blo(a0.z) + blo(a1.z)) + (blo(a2.z) + blo(a3.z));
        acc[5] += (bhi(a0.z) + bhi(a1.z)) + (bhi(a2.z) + bhi(a3.z));
        acc[6] += (blo(a0.w) + blo(a1.w)) + (blo(a2.w) + blo(a3.w));
        acc[7] += (bhi(a0.w) + bhi(a1.w)) + (bhi(a2.w) + bhi(a3.w));
    }
    if (k + 8 <= dg) {
        int s0 = csr[off + k + ng];
        int s1 = csr[off + k + 4 + ng];
        uint4 a0 = *(const uint4*)(tl + (size_t)s0 * 16 + 4 * fl);
        uint4 a1 = *(const uint4*)(tl + (size_t)s1 * 16 + 4 * fl);
        acc[0] += blo(a0.x) + blo(a1.x); acc[1] += bhi(a0.x) + bhi(a1.x);
        acc[2] += blo(a0.y) + blo(a1.y); acc[3] += bhi(a0.y) + bhi(a1.y);
        acc[4] += blo(a0.z) + blo(a1.z); acc[5] += bhi(a0.z) + bhi(a1.z);
        acc[6] += blo(a0.w) + blo(a1.w); acc[7] += bhi(a0.w) + bhi(a1.w);
        k += 8;
    }
    if (k + 4 <= dg) {
        int s0 = csr[off + k + ng];
        uint4 a0 = *(const uint4*)(tl + (size_t)s0 * 16 + 4 * fl);
        acc[0] += blo(a0.x); acc[1] += bhi(a0.x);
        acc[2] += blo(a0.y); acc[3] += bhi(a0.y);
        acc[4] += blo(a0.z); acc[5] += bhi(a0.z);
        acc[6] += blo(a0.w); acc[7] += bhi(a0.w);
        k += 4;
    }
    if (ng < dg - k) {
        int s0 = csr[off + k + ng];
        uint4 a0 = *(const uint4*)(tl + (size_t)s0 * 16 + 4 * fl);
        acc[0] += blo(a0.x); acc[1] += bhi(a0.x);
        acc[2] += blo(a0.y); acc[3] += bhi(a0.y);
        acc[4] += blo(a0.z); acc[5] += bhi(a0.z);
        acc[6] += blo(a0.w); acc[7] += bhi(a0.w);
    }
}

// ---------------- chunked aggregation (layers 0,1 -> bf16 next-layer input) -----------
template <int D>
__launch_bounds__(256) static __global__
void agg3_kernel(const ushort_t* __restrict__ tlc, const ushort_t* __restrict__ trc,
                 const int* __restrict__ offs, const int* __restrict__ deg,
                 const int* __restrict__ csr, ushort_t* __restrict__ outb) {
    int bx = blockIdx.x;
    int c = bx / AGB;
    int b = bx - c * AGB;
    int tid = threadIdx.x;
    int node = b * 16 + (tid >> 4);
    int lane = tid & 15;
    int ng = lane >> 2, fl = lane & 3;
    const uint_t* tl = (const uint_t*)tlc + (size_t)c * NN * 16;
    int off = offs[node], dg = deg[node];
    float acc[8];
#pragma unroll
    for (int q = 0; q < 8; q++) acc[q] = 0.f;
    gather_accum(tl, csr, off, dg, ng, fl, acc);
#pragma unroll
    for (int q = 0; q < 8; q++) {
        acc[q] += __shfl_xor(acc[q], 4, 64);
        acc[q] += __shfl_xor(acc[q], 8, 64);
    }
    float s = 1.f / (float)max(dg, 1);
    u32x4 t = __builtin_nontemporal_load(
        (const u32x4*)((const uint_t*)trc + (size_t)c * NN * 16 + (size_t)node * 16 + 4 * fl));
    float v0 = fmaxf(fmaf(acc[0], s, blo(t.x)), 0.f);
    float v1 = fmaxf(fmaf(acc[1], s, bhi(t.x)), 0.f);
    float v2 = fmaxf(fmaf(acc[2], s, blo(t.y)), 0.f);
    float v3 = fmaxf(fmaf(acc[3], s, bhi(t.y)), 0.f);
    float v4 = fmaxf(fmaf(acc[4], s, blo(t.z)), 0.f);
    float v5 = fmaxf(fmaf(acc[5], s, bhi(t.z)), 0.f);
    float v6 = fmaxf(fmaf(acc[6], s, blo(t.w)), 0.f);
    float v7 = fmaxf(fmaf(acc[7], s, bhi(t.w)), 0.f);
    if (ng == 0) {
        u32x4 o;
        o.x = (uint_t)f2b(v0) | ((uint_t)f2b(v1) << 16);
        o.y = (uint_t)f2b(v2) | ((uint_t)f2b(v3) << 16);
        o.z = (uint_t)f2b(v4) | ((uint_t)f2b(v5) << 16);
        o.w = (uint_t)f2b(v6) | ((uint_t)f2b(v7) << 16);
        __builtin_nontemporal_store(
            o, (u32x4*)((uint_t*)outb + (size_t)node * (D / 2) + c * 16 + 4 * fl));
    }
}

// ---------------- final agg + pool fused (D=64, no relu), pre-divided atomics -------
// Block's 16 nodes contiguous + batch sorted -> 1-2 graphs/block. Stage 16x32
// fp32 in LDS, 32 walkers run-length reduce by graph id, atomicAdd of
// ps * inv_cnt[g] straight into d_out (no finalize dispatch).
__launch_bounds__(256) static __global__
void agg_pool_kernel(const ushort_t* __restrict__ tlc, const ushort_t* __restrict__ trc,
                     const int* __restrict__ offs, const int* __restrict__ deg,
                     const int* __restrict__ csr, const int* __restrict__ batch,
                     const float* __restrict__ inv_cnt, float* __restrict__ out) {
    __shared__ float hsum[16][32];
    __shared__ int gids[16];
    int bx = blockIdx.x;
    int c = bx / AGB;
    int b = bx - c * AGB;
    int tid = threadIdx.x;
    int nl = tid >> 4;
    int node = b * 16 + nl;
    int lane = tid & 15;
    int ng = lane >> 2, fl = lane & 3;
    if (tid < 16) gids[tid] = batch[b * 16 + tid];
    const uint_t* tl = (const uint_t*)tlc + (size_t)c * NN * 16;
    int off = offs[node], dg = deg[node];
    float acc[8];
#pragma unroll
    for (int q = 0; q < 8; q++) acc[q] = 0.f;
    gather_accum(tl, csr, off, dg, ng, fl, acc);
#pragma unroll
    for (int q = 0; q < 8; q++) {
        acc[q] += __shfl_xor(acc[q], 4, 64);
        acc[q] += __shfl_xor(acc[q], 8, 64);
    }
    float s = 1.f / (float)max(dg, 1);
    u32x4 t = __builtin_nontemporal_load(
        (const u32x4*)((const uint_t*)trc + (size_t)c * NN * 16 + (size_t)node * 16 + 4 * fl));
    if (ng == 0) {
        hsum[nl][8 * fl + 0] = fmaf(acc[0], s, blo(t.x));
        hsum[nl][8 * fl + 1] = fmaf(acc[1], s, bhi(t.x));
        hsum[nl][8 * fl + 2] = fmaf(acc[2], s, blo(t.y));
        hsum[nl][8 * fl + 3] = fmaf(acc[3], s, bhi(t.y));
        hsum[nl][8 * fl + 4] = fmaf(acc[4], s, blo(t.z));
        hsum[nl][8 * fl + 5] = fmaf(acc[5], s, bhi(t.z));
        hsum[nl][8 * fl + 6] = fmaf(acc[6], s, blo(t.w));
        hsum[nl][8 * fl + 7] = fmaf(acc[7], s, bhi(t.w));
    }
    __syncthreads();
    if (tid < 32) {
        int gcur = gids[0];
        float ps = 0.f;
        for (int j = 0; j < 16; j++) {
            int g = gids[j];
            if (g != gcur) {
                atomicAdd(&out[gcur * 64 + c * 32 + tid], ps * inv_cnt[gcur]);
                ps = 0.f; gcur = g;
            }
            ps += hsum[j][tid];
        }
        atomicAdd(&out[gcur * 64 + c * 32 + tid], ps * inv_cnt[gcur]);
    }
}

// ---------------- launch ----------------
extern "C" void kernel_launch(void* const* d_in, const int* in_sizes, int n_in,
                              void* d_out, int out_size, void* d_ws, size_t ws_size,
                              hipStream_t stream) {
    (void)in_sizes; (void)n_in; (void)out_size; (void)ws_size;
    const float* x   = (const float*)d_in[0];
    const int*   ei  = (const int*)d_in[1];
    const int*   bat = (const int*)d_in[2];
    const float* Wl0 = (const float*)d_in[3];
    const float* b0  = (const float*)d_in[4];
    const float* Wr0 = (const float*)d_in[5];
    const float* Wl1 = (const float*)d_in[6];
    const float* b1  = (const float*)d_in[7];
    const float* Wr1 = (const float*)d_in[8];
    const float* Wl2 = (const float*)d_in[9];
    const float* b2  = (const float*)d_in[10];
    const float* Wr2 = (const float*)d_in[11];
    float* out = (float*)d_out;
    const int* src = ei;
    const int* dst = ei + NE;

    char* p = (char*)d_ws;
    auto carve = [&](size_t bytes) -> char* {
        char* r = p;
        p += (bytes + 255) & ~(size_t)255;
        return r;
    };
    int*      deg    = (int*)carve((size_t)NN * 4);
    int*      offs   = (int*)carve((size_t)NN * 4);
    int*      bucket_cnt = (int*)carve(NBKT * 4);
    float*    inv_cnt = (float*)carve(NG * 4);
    uint_t*   part   = (uint_t*)carve((size_t)NBKT * BCAP * 4);
    int*      csr    = (int*)carve((size_t)NE * 4);
    ushort_t* h1b    = (ushort_t*)carve((size_t)NP * 96 * 2);   // layer-1 input
    ushort_t* h2b    = (ushort_t*)carve((size_t)NP * 96 * 2);   // layer-2 input
    ushort_t* tlc    = (ushort_t*)carve((size_t)3 * NN * 32 * 2);  // chunk-major
    ushort_t* trc    = (ushort_t*)carve((size_t)3 * NN * 32 * 2);  // chunk-major

    dim3 b256(256);
    hipMemsetAsync(bucket_cnt, 0, NBKT * 4, stream);

    part_zero_kernel<<<dim3(PARTB + 32), b256, 0, stream>>>(src, dst, bucket_cnt, part,
                                                            out, bat, inv_cnt);
    csr_tf0_kernel<<<dim3(NBKT + TFB), b256, 0, stream>>>(part, bucket_cnt, deg, offs, csr,
                                                          x, Wl0, b0, Wr0, tlc, trc);
    agg3_kernel<96><<<dim3(3 * AGB), b256, 0, stream>>>(tlc, trc, offs, deg, csr, h1b);
    transform_kernel<96, 12><<<dim3(TFB), b256, 0, stream>>>(h1b, Wl1, b1, Wr1, tlc, trc);
    agg3_kernel<96><<<dim3(3 * AGB), b256, 0, stream>>>(tlc, trc, offs, deg, csr, h2b);
    transform_kernel<64, 8><<<dim3(TFB), b256, 0, stream>>>(h2b, Wl2, b2, Wr2, tlc, trc);
    agg_pool_kernel<<<dim3(2 * AGB), b256, 0, stream>>>(tlc, trc, offs, deg, csr, bat,
                                                        inv_cnt, out);
}